// Round 10
// baseline (140.797 us; speedup 1.0000x reference)
//
#include <hip/hip_runtime.h>
#include <math.h>

namespace {

constexpr int RAD  = 6;
constexpr int P    = 13;
constexpr int NWIN = 169;   // P*P
constexpr int NTOT = 338;   // 2 refs * NWIN
constexpr int NCH  = 128;
constexpr int NCLS = 32;
constexpr int W    = 64;
constexpr int HW   = 4096;
constexpr float FOUR_LN2 = 2.772588722239781f;

// ---- kernel A tiling ----
constexpr int TX    = 32;            // pixels per block (half row)
constexpr int CHUNK = 8;             // channels per stage
constexpr int BCH   = 64;            // channels per block (x2 channel split)
constexpr int NCHUNK2 = BCH / CHUNK; // 8 chunks
constexpr int PW    = 44;            // patch width (16B-aligned rows, no extra pad)
constexpr int PR    = 13;            // patch rows (dy)
constexpr int FRELEMS = CHUNK * PR * PW;   // 4576
constexpr int NLD   = 18;            // ceil(4576/256)
constexpr int TILE  = TX * NWIN;           // 5408 floats
constexpr size_t VOLH = (size_t)2 * HW * NTOT;  // floats per partial volume

__device__ __forceinline__ bool better(float va, int ia, float vb, int ib) {
  return (va > vb) || ((va == vb) && (ia < ib));
}

// ================= Kernel A: correlation volume (partial channels) =========
// grid: (((bi)*64 + y)*2 + xh)*2 + h   (1024 blocks), 256 threads
// block computes channels [h*64, h*64+64) and writes vol_h (partial sums).
__global__ __launch_bounds__(256, 4) void corr_kernel(
    const float* __restrict__ fr,   // [2][2][128][64][64]  (nref,b,c,y,x)
    const float* __restrict__ ft,   // [2][128][64][64]
    float* __restrict__ vol) {
  const int blk = blockIdx.x;
  const int h  = blk & 1;
  const int xh = (blk >> 1) & 1;
  const int y  = (blk >> 2) & 63;
  const int bi = blk >> 8;             // b*2+i
  const int b  = bi >> 1;
  const int ii = bi & 1;
  const int x0 = xh * TX;
  const int t  = threadIdx.x;
  const int cg = t >> 7;               // channel group 0/1
  const int tl = t & 127;

  __shared__ __align__(16) float smem[2 * FRELEMS];     // 36608 B
  __shared__ __align__(16) float ftbuf[2][CHUNK * TX];   // 2048 B

  const int xg = tl & 7;               // x-quad within half row
  const int dy = tl >> 3;              // 0..12 valid when tl<104
  const bool comp = (tl < 104);

  // fr outer layout is [nref][b]; channel offset h*64
  const float* frbase = fr + (size_t)((ii * 2 + b) * NCH + h * BCH) * HW;
  const float* ftp = ft + (size_t)(b * NCH + h * BCH + (t >> 5)) * HW + y * W + x0 + (t & 31);

  // ---- hoisted staging offsets (u16-packed; loop-invariant across chunks) ----
  unsigned offp[9];
  unsigned vmsk = 0u;
  #pragma unroll
  for (int u = 0; u < NLD; ++u) {
    const int e = t + u * 256;
    unsigned o = 0;
    if (e < FRELEMS) {
      const int cc  = e / (PR * PW);
      const int rem = e - cc * (PR * PW);
      const int r   = rem / PW;
      const int xc  = rem - r * PW;
      const int yy  = y + r - RAD;
      const int xx  = x0 - RAD + xc;
      if ((unsigned)yy < 64u && (unsigned)xx < 64u) {
        o = (unsigned)(cc * HW + yy * W + xx);     // < 8*4096+4095 < 65536
        vmsk |= (1u << u);
      }
    }
    if (u & 1) offp[u >> 1] |= (o << 16); else offp[u >> 1] = o;
  }

  float acc[13][4];
  #pragma unroll
  for (int dx = 0; dx < 13; ++dx)
    #pragma unroll
    for (int k = 0; k < 4; ++k) acc[dx][k] = 0.f;

  float rg[NLD];
  float rft;

  auto stage_load = [&](int c0) {
    const float* fb = frbase + (size_t)c0 * HW;
    #pragma unroll
    for (int u = 0; u < NLD; ++u) {
      const int o = (u & 1) ? (int)(offp[u >> 1] >> 16) : (int)(offp[u >> 1] & 0xffffu);
      const float v = fb[o];
      rg[u] = (vmsk & (1u << u)) ? v : 0.f;
    }
    rft = ftp[(size_t)c0 * HW];
  };
  auto stage_write = [&](int s) {
    float* frb = smem + s * FRELEMS;
    #pragma unroll
    for (int u = 0; u < NLD; ++u) {
      const int e = t + u * 256;
      if (e < FRELEMS) frb[e] = rg[u];
    }
    ftbuf[s][t] = rft;
  };

  stage_load(0);
  stage_write(0);
  __syncthreads();

  for (int k = 0; k < NCHUNK2; ++k) {
    const int cur = k & 1;
    if (k < NCHUNK2 - 1) stage_load((k + 1) * CHUNK);
    if (comp) {
      const float* frb = smem + cur * FRELEMS;
      #pragma unroll
      for (int c2 = 0; c2 < 4; ++c2) {
        const int cc = cg * 4 + c2;
        const float* fp = frb + (cc * PR + dy) * PW + xg * 4;
        float w[16];
        #pragma unroll
        for (int j = 0; j < 4; ++j) {
          const float4 q4 = *(const float4*)(fp + 4 * j);
          w[4 * j] = q4.x; w[4 * j + 1] = q4.y; w[4 * j + 2] = q4.z; w[4 * j + 3] = q4.w;
        }
        const float4 tq = *(const float4*)(&ftbuf[cur][cc * TX + xg * 4]);
        const float tqa[4] = {tq.x, tq.y, tq.z, tq.w};
        #pragma unroll
        for (int dx = 0; dx < 13; ++dx)
          #pragma unroll
          for (int kk = 0; kk < 4; ++kk)
            acc[dx][kk] = fmaf(w[dx + kk], tqa[kk], acc[dx][kk]);
      }
    }
    // write(k) targets buf cur^1, last read by compute(k-1) — separated by
    // the previous iteration's barrier; compute(k) reads buf cur. One
    // barrier per chunk suffices.
    if (k < NCHUNK2 - 1) stage_write(cur ^ 1);
    __syncthreads();
  }

  // --- cross-cg reduction (staging buffers dead now) ---
  if (comp && cg == 1) {
    float* rb = smem + tl * 52;
    #pragma unroll
    for (int dx = 0; dx < 13; ++dx)
      *(float4*)(rb + dx * 4) = make_float4(acc[dx][0], acc[dx][1], acc[dx][2], acc[dx][3]);
  }
  __syncthreads();
  if (comp && cg == 0) {
    const float* rb = smem + tl * 52;
    #pragma unroll
    for (int dx = 0; dx < 13; ++dx) {
      const float4 r = *(const float4*)(rb + dx * 4);
      acc[dx][0] += r.x; acc[dx][1] += r.y; acc[dx][2] += r.z; acc[dx][3] += r.w;
    }
  }
  __syncthreads();
  if (comp && cg == 0) {
    #pragma unroll
    for (int dx = 0; dx < 13; ++dx)
      #pragma unroll
      for (int kk = 0; kk < 4; ++kk)
        smem[(xg * 4 + kk) * NWIN + dy * 13 + dx] = acc[dx][kk];
  }
  __syncthreads();
  {
    float* gb = vol + (size_t)h * VOLH + ((size_t)(b * HW + y * W + x0) * 2 + ii) * NWIN;
    for (int u = 0; u < 22; ++u) {
      const int e = t + u * 256;
      if (e < TILE) {
        const int xl2 = e / NWIN;
        const int mm  = e - xl2 * NWIN;
        gb[(size_t)xl2 * (2 * NWIN) + mm] = smem[e];
      }
    }
  }
}

// ================= Kernel L: dense down-sampled label map =================
__global__ __launch_bounds__(256) void lab_kernel(
    const int* __restrict__ q, int* __restrict__ lab) {
  const int idx = blockIdx.x * 256 + threadIdx.x;   // 0..16383
  const int i2b = idx >> 12;
  const int rem = idx & 4095;
  const int yy  = rem >> 6;
  const int xx  = rem & 63;
  lab[idx] = q[(size_t)i2b * 65536 + (yy * 4) * 256 + xx * 4];
}

// ================= Kernel B: wave-per-pixel post-processing =================
__global__ __launch_bounds__(256) void post_kernel(
    const float* __restrict__ vol,  // two partials: [h][pix][2][169]
    const int*  __restrict__ lab,   // [4][64][64]
    float* __restrict__ out) {      // [2][32][64][64]
  const int blk  = blockIdx.x;
  const int t    = threadIdx.x;
  const int w    = t >> 6;
  const int lane = t & 63;
  const int pix  = blk * 4 + w;
  const int b = pix >> 12;
  const int y = (pix >> 6) & 63;
  const int x = pix & 63;

  __shared__ float accS[4][NCLS];
  accS[w][lane & 31] = 0.f;

  float vv[6];
  float lmax = -INFINITY;
  const float* vp = vol + (size_t)pix * NTOT;
  #pragma unroll
  for (int k = 0; k < 6; ++k) {
    const int e = lane + 64 * k;
    vv[k] = (e < NTOT) ? (vp[e] + vp[VOLH + e]) : -INFINITY;
    lmax = fmaxf(lmax, vv[k]);
  }
  #pragma unroll
  for (int off = 32; off > 0; off >>= 1)
    lmax = fmaxf(lmax, __shfl_xor(lmax, off));

  float p[6];
  float lsum = 0.f;
  #pragma unroll
  for (int k = 0; k < 6; ++k) {
    const int e = lane + 64 * k;
    p[k] = (e < NTOT) ? __expf(vv[k] - lmax) : 0.f;
    lsum += p[k];
  }
  #pragma unroll
  for (int off = 32; off > 0; off >>= 1)
    lsum += __shfl_xor(lsum, off);
  const float rinv = 1.f / lsum;
  #pragma unroll
  for (int k = 0; k < 6; ++k) p[k] *= rinv;

  float a1_0 = -1.f, a2_0 = -1.f, a1_1 = -1.f, a2_1 = -1.f;
  int   j1_0 = 1 << 20, j2_0 = 1 << 20, j1_1 = 1 << 20, j2_1 = 1 << 20;
  #pragma unroll
  for (int k = 0; k < 6; ++k) {
    const int e = lane + 64 * k;
    if (e < NTOT) {
      const int r = (e >= NWIN) ? 1 : 0;
      const int m = e - r * NWIN;
      const float pv = p[k];
      if (r == 0) {
        if (better(pv, m, a1_0, j1_0)) { a2_0 = a1_0; j2_0 = j1_0; a1_0 = pv; j1_0 = m; }
        else if (better(pv, m, a2_0, j2_0)) { a2_0 = pv; j2_0 = m; }
      } else {
        if (better(pv, m, a1_1, j1_1)) { a2_1 = a1_1; j2_1 = j1_1; a1_1 = pv; j1_1 = m; }
        else if (better(pv, m, a2_1, j2_1)) { a2_1 = pv; j2_1 = m; }
      }
    }
  }
  #pragma unroll
  for (int off = 32; off > 0; off >>= 1) {
    {
      const float u1 = __shfl_xor(a1_0, off); const int q1 = __shfl_xor(j1_0, off);
      const float u2 = __shfl_xor(a2_0, off); const int q2 = __shfl_xor(j2_0, off);
      if (better(u1, q1, a1_0, j1_0)) {
        float nv2; int ni2;
        if (better(a1_0, j1_0, u2, q2)) { nv2 = a1_0; ni2 = j1_0; }
        else                            { nv2 = u2;   ni2 = q2; }
        a1_0 = u1; j1_0 = q1; a2_0 = nv2; j2_0 = ni2;
      } else if (better(u1, q1, a2_0, j2_0)) { a2_0 = u1; j2_0 = q1; }
    }
    {
      const float u1 = __shfl_xor(a1_1, off); const int q1 = __shfl_xor(j1_1, off);
      const float u2 = __shfl_xor(a2_1, off); const int q2 = __shfl_xor(j2_1, off);
      if (better(u1, q1, a1_1, j1_1)) {
        float nv2; int ni2;
        if (better(a1_1, j1_1, u2, q2)) { nv2 = a1_1; ni2 = j1_1; }
        else                            { nv2 = u2;   ni2 = q2; }
        a1_1 = u1; j1_1 = q1; a2_1 = nv2; j2_1 = ni2;
      } else if (better(u1, q1, a2_1, j2_1)) { a2_1 = u1; j2_1 = q1; }
    }
  }

  const float e10 = __expf(a1_0), e20 = __expf(a2_0);
  const float rs0 = 1.f / (e10 + e20);
  const float w00 = e10 * rs0, w10 = e20 * rs0;
  const bool  fl0 = (a1_0 > 0.1f);
  const float xs00 = (float)(j1_0 % P), ys00 = (float)(j1_0 / P);
  const float xs10 = (float)(j2_0 % P), ys10 = (float)(j2_0 / P);

  const float e11 = __expf(a1_1), e21 = __expf(a2_1);
  const float rs1 = 1.f / (e11 + e21);
  const float w01 = e11 * rs1, w11 = e21 * rs1;
  const bool  fl1 = (a1_1 > 0.1f);
  const float xs01 = (float)(j1_1 % P), ys01 = (float)(j1_1 / P);
  const float xs11 = (float)(j2_1 % P), ys11 = (float)(j2_1 / P);

  #pragma unroll
  for (int k = 0; k < 6; ++k) {
    const int e = lane + 64 * k;
    if (e < NTOT) {
      const int r  = (e >= NWIN) ? 1 : 0;
      const int m  = e - r * NWIN;
      const int dy = m / P;
      const int dx = m - dy * P;
      const bool  fl = r ? fl1 : fl0;
      float val;
      if (fl) {
        const float wA = r ? w01 : w00, wB = r ? w11 : w10;
        const float xA = r ? xs01 : xs00, yA = r ? ys01 : ys00;
        const float xB = r ? xs11 : xs10, yB = r ? ys11 : ys10;
        const float fdx0 = (float)dx - xA, fdy0 = (float)dy - yA;
        const float fdx1 = (float)dx - xB, fdy1 = (float)dy - yB;
        val = wA * __expf(-FOUR_LN2 * (fdx0 * fdx0 + fdy0 * fdy0))
            + wB * __expf(-FOUR_LN2 * (fdx1 * fdx1 + fdy1 * fdy1));
      } else {
        val = p[k];
      }
      const int yy = y + dy - RAD;
      const int xx = x + dx - RAD;
      if ((unsigned)yy < 64u && (unsigned)xx < 64u) {
        const int cls = lab[(size_t)(r * 2 + b) * 4096 + yy * W + xx];
        atomicAdd(&accS[w][cls], val);
      }
    }
  }
  __syncthreads();

  if (t < 4 * NCLS) {
    const int cls = t >> 2;
    const int j   = t & 3;
    const int x0  = (blk * 4) & 63;
    const float sc = (cls == 0) ? 1.0f : 1.15f;
    out[(size_t)(b * NCLS + cls) * HW + y * W + x0 + j] = accS[j][cls] * sc;
  }
}

}  // namespace

extern "C" void kernel_launch(void* const* d_in, const int* in_sizes, int n_in,
                              void* d_out, int out_size, void* d_ws, size_t ws_size,
                              hipStream_t stream) {
  const float* fr = (const float*)d_in[0];   // feats_r
  const float* ft = (const float*)d_in[1];   // feats_t
  const int*   q  = (const int*)d_in[2];     // quantized_r
  float* out = (float*)d_out;
  float* vol = (float*)d_ws;                             // 2 partials x 11.07 MB
  int*   lab = (int*)((char*)d_ws + 2 * VOLH * sizeof(float)); // +64 KB

  lab_kernel<<<dim3(64), dim3(256), 0, stream>>>(q, lab);
  corr_kernel<<<dim3(2 * 2 * 64 * 2 * 2), dim3(256), 0, stream>>>(fr, ft, vol);
  post_kernel<<<dim3(2 * HW / 4), dim3(256), 0, stream>>>(vol, lab, out);
}

// Round 11
// 66.271 us; speedup vs baseline: 2.1246x; 2.1246x over previous
//
#include <hip/hip_runtime.h>
#include <math.h>

namespace {

constexpr int RAD  = 6;
constexpr int P    = 13;
constexpr int NWIN = 169;   // P*P
constexpr int NTOT = 338;   // 2 refs * NWIN
constexpr int NCH  = 128;
constexpr int NCLS = 32;
constexpr int W    = 64;
constexpr int HW   = 4096;
constexpr float FOUR_LN2 = 2.772588722239781f;

// ---- kernel A tiling (R9-proven geometry) ----
constexpr int TX    = 32;            // pixels per block (half row)
constexpr int CHUNK = 8;             // channels per stage
constexpr int PW    = 48;            // patch width: 44 used + 4 pad
constexpr int PR    = 13;            // patch rows (dy)
constexpr int FRELEMS = CHUNK * PR * PW;   // 4992 (= 78 waves of 64 -> uniform guards)
constexpr int NLD   = 20;            // ceil(4992/256)
constexpr int NCHUNK = NCH / CHUNK;  // 16
constexpr int TILE  = TX * NWIN;     // 5408 floats
constexpr size_t VOLF = (size_t)2 * HW * NTOT;  // floats in volume

typedef const __attribute__((address_space(1))) void* gas_t;
typedef __attribute__((address_space(3))) void*       las_t;

__device__ __forceinline__ bool better(float va, int ia, float vb, int ib) {
  return (va > vb) || ((va == vb) && (ia < ib));
}

// ================= Kernel A: correlation volume =================
// grid: ((b*2+i)*64 + y)*2 + xh   (512 blocks), 256 threads
// Staging via global_load_lds (async, no register round-trip).
__global__ __launch_bounds__(256, 2) void corr_kernel(
    const float* __restrict__ fr,   // [2][2][128][64][64]  (nref,b,c,y,x)
    const float* __restrict__ ft,   // [2][128][64][64]
    float* __restrict__ vol,
    const float* __restrict__ zp) { // zeroed page for OOB halo lanes
  const int blk = blockIdx.x;
  const int xh = blk & 1;
  const int y  = (blk >> 1) & 63;
  const int bi = blk >> 7;             // b*2+i
  const int b  = bi >> 1;
  const int ii = bi & 1;
  const int x0 = xh * TX;
  const int t  = threadIdx.x;
  const int cg = t >> 7;               // channel group 0/1
  const int tl = t & 127;

  __shared__ __align__(16) float smem[2 * FRELEMS];     // 39936 B
  __shared__ __align__(16) float ftbuf[2][CHUNK * TX];  // 2048 B

  const int xg = tl & 7;               // x-quad within half row
  const int dy = tl >> 3;              // 0..12 valid when tl<104
  const bool comp = (tl < 104);

  // fr outer layout is [nref][b] -> index ii*2+b
  const float* frbase = fr + (size_t)((ii * 2 + b) * NCH) * HW;
  const float* ftp = ft + (size_t)(b * NCH + (t >> 5)) * HW + y * W + x0 + (t & 31);

  // ---- hoisted per-lane staging addresses (loop-invariant shape) ----
  const float* ga[NLD];
  unsigned vmsk = 0u;
  #pragma unroll
  for (int u = 0; u < NLD; ++u) {
    const int e = t + u * 256;
    const float* a = zp;               // OOB halo -> zero page
    if (e < FRELEMS) {
      const int cc  = e / (PR * PW);
      const int rem = e - cc * (PR * PW);
      const int r   = rem / PW;
      const int xc  = rem - r * PW;
      const int yy  = y + r - RAD;
      const int xx  = x0 - RAD + xc;
      if ((unsigned)yy < 64u && (unsigned)xx < 64u && xc < 44) {
        a = frbase + cc * HW + yy * W + xx;
        vmsk |= (1u << u);
      }
    }
    ga[u] = a;
  }

  float acc[13][4];
  #pragma unroll
  for (int dx = 0; dx < 13; ++dx)
    #pragma unroll
    for (int k = 0; k < 4; ++k) acc[dx][k] = 0.f;

  // ---- async stage: issue global->LDS directly (no reg round-trip) ----
  auto stage_issue = [&](int s) {
    float* frb = smem + s * FRELEMS;
    #pragma unroll
    for (int u = 0; u < NLD; ++u) {
      const int e = t + u * 256;
      if (e < FRELEMS) {               // wave-uniform (4992 % 64 == 0)
        __builtin_amdgcn_global_load_lds((gas_t)ga[u], (las_t)(frb + e), 4, 0, 0);
      }
    }
    __builtin_amdgcn_global_load_lds((gas_t)ftp, (las_t)(&ftbuf[s][t]), 4, 0, 0);
  };
  auto stage_advance = [&]() {
    #pragma unroll
    for (int u = 0; u < NLD; ++u)
      ga[u] += ((vmsk >> u) & 1u) ? (CHUNK * HW) : 0;   // zp lanes stay put
    ftp += (size_t)CHUNK * HW;
  };

  stage_issue(0);
  stage_advance();
  __syncthreads();                      // drains prologue loads

  for (int k = 0; k < NCHUNK; ++k) {
    const int cur = k & 1;
    if (k < NCHUNK - 1) {               // issue next chunk under compute
      stage_issue(cur ^ 1);
      stage_advance();
    }
    if (comp) {
      const float* frb = smem + cur * FRELEMS;
      #pragma unroll
      for (int c2 = 0; c2 < 4; ++c2) {
        const int cc = cg * 4 + c2;
        const float* fp = frb + (cc * PR + dy) * PW + xg * 4;
        float w[16];
        #pragma unroll
        for (int j = 0; j < 4; ++j) {
          const float4 q4 = *(const float4*)(fp + 4 * j);
          w[4 * j] = q4.x; w[4 * j + 1] = q4.y; w[4 * j + 2] = q4.z; w[4 * j + 3] = q4.w;
        }
        const float4 tq = *(const float4*)(&ftbuf[cur][cc * TX + xg * 4]);
        const float tqa[4] = {tq.x, tq.y, tq.z, tq.w};
        #pragma unroll
        for (int dx = 0; dx < 13; ++dx)
          #pragma unroll
          for (int kk = 0; kk < 4; ++kk)
            acc[dx][kk] = fmaf(w[dx + kk], tqa[kk], acc[dx][kk]);
      }
    }
    __syncthreads();   // orders buffer reuse AND drains in-flight loads (vmcnt)
  }

  // --- cross-cg reduction (staging buffers dead now) ---
  if (comp && cg == 1) {
    float* rb = smem + tl * 52;
    #pragma unroll
    for (int dx = 0; dx < 13; ++dx)
      *(float4*)(rb + dx * 4) = make_float4(acc[dx][0], acc[dx][1], acc[dx][2], acc[dx][3]);
  }
  __syncthreads();
  if (comp && cg == 0) {
    const float* rb = smem + tl * 52;
    #pragma unroll
    for (int dx = 0; dx < 13; ++dx) {
      const float4 r = *(const float4*)(rb + dx * 4);
      acc[dx][0] += r.x; acc[dx][1] += r.y; acc[dx][2] += r.z; acc[dx][3] += r.w;
    }
  }
  __syncthreads();
  if (comp && cg == 0) {
    #pragma unroll
    for (int dx = 0; dx < 13; ++dx)
      #pragma unroll
      for (int kk = 0; kk < 4; ++kk)
        smem[(xg * 4 + kk) * NWIN + dy * 13 + dx] = acc[dx][kk];
  }
  __syncthreads();
  {
    float* gb = vol + ((size_t)(b * HW + y * W + x0) * 2 + ii) * NWIN;
    for (int u = 0; u < 22; ++u) {
      const int e = t + u * 256;
      if (e < TILE) {
        const int xl2 = e / NWIN;
        const int mm  = e - xl2 * NWIN;
        gb[(size_t)xl2 * (2 * NWIN) + mm] = smem[e];
      }
    }
  }
}

// ================= Kernel L: label map + zero page =================
__global__ __launch_bounds__(256) void lab_kernel(
    const int* __restrict__ q, int* __restrict__ lab, float* __restrict__ zp) {
  const int idx = blockIdx.x * 256 + threadIdx.x;   // 0..16383
  const int i2b = idx >> 12;
  const int rem = idx & 4095;
  const int yy  = rem >> 6;
  const int xx  = rem & 63;
  lab[idx] = q[(size_t)i2b * 65536 + (yy * 4) * 256 + xx * 4];
  if (idx < 1024) zp[idx] = 0.f;
}

// ================= Kernel B: wave-per-pixel post-processing =================
__global__ __launch_bounds__(256) void post_kernel(
    const float* __restrict__ vol,  // [pix][2][169]
    const int*  __restrict__ lab,   // [4][64][64]
    float* __restrict__ out) {      // [2][32][64][64]
  const int blk  = blockIdx.x;
  const int t    = threadIdx.x;
  const int w    = t >> 6;
  const int lane = t & 63;
  const int pix  = blk * 4 + w;
  const int b = pix >> 12;
  const int y = (pix >> 6) & 63;
  const int x = pix & 63;

  __shared__ float accS[4][NCLS];
  accS[w][lane & 31] = 0.f;

  float vv[6];
  float lmax = -INFINITY;
  const float* vp = vol + (size_t)pix * NTOT;
  #pragma unroll
  for (int k = 0; k < 6; ++k) {
    const int e = lane + 64 * k;
    vv[k] = (e < NTOT) ? vp[e] : -INFINITY;
    lmax = fmaxf(lmax, vv[k]);
  }
  #pragma unroll
  for (int off = 32; off > 0; off >>= 1)
    lmax = fmaxf(lmax, __shfl_xor(lmax, off));

  float p[6];
  float lsum = 0.f;
  #pragma unroll
  for (int k = 0; k < 6; ++k) {
    const int e = lane + 64 * k;
    p[k] = (e < NTOT) ? __expf(vv[k] - lmax) : 0.f;
    lsum += p[k];
  }
  #pragma unroll
  for (int off = 32; off > 0; off >>= 1)
    lsum += __shfl_xor(lsum, off);
  const float rinv = 1.f / lsum;
  #pragma unroll
  for (int k = 0; k < 6; ++k) p[k] *= rinv;

  float a1_0 = -1.f, a2_0 = -1.f, a1_1 = -1.f, a2_1 = -1.f;
  int   j1_0 = 1 << 20, j2_0 = 1 << 20, j1_1 = 1 << 20, j2_1 = 1 << 20;
  #pragma unroll
  for (int k = 0; k < 6; ++k) {
    const int e = lane + 64 * k;
    if (e < NTOT) {
      const int r = (e >= NWIN) ? 1 : 0;
      const int m = e - r * NWIN;
      const float pv = p[k];
      if (r == 0) {
        if (better(pv, m, a1_0, j1_0)) { a2_0 = a1_0; j2_0 = j1_0; a1_0 = pv; j1_0 = m; }
        else if (better(pv, m, a2_0, j2_0)) { a2_0 = pv; j2_0 = m; }
      } else {
        if (better(pv, m, a1_1, j1_1)) { a2_1 = a1_1; j2_1 = j1_1; a1_1 = pv; j1_1 = m; }
        else if (better(pv, m, a2_1, j2_1)) { a2_1 = pv; j2_1 = m; }
      }
    }
  }
  #pragma unroll
  for (int off = 32; off > 0; off >>= 1) {
    {
      const float u1 = __shfl_xor(a1_0, off); const int q1 = __shfl_xor(j1_0, off);
      const float u2 = __shfl_xor(a2_0, off); const int q2 = __shfl_xor(j2_0, off);
      if (better(u1, q1, a1_0, j1_0)) {
        float nv2; int ni2;
        if (better(a1_0, j1_0, u2, q2)) { nv2 = a1_0; ni2 = j1_0; }
        else                            { nv2 = u2;   ni2 = q2; }
        a1_0 = u1; j1_0 = q1; a2_0 = nv2; j2_0 = ni2;
      } else if (better(u1, q1, a2_0, j2_0)) { a2_0 = u1; j2_0 = q1; }
    }
    {
      const float u1 = __shfl_xor(a1_1, off); const int q1 = __shfl_xor(j1_1, off);
      const float u2 = __shfl_xor(a2_1, off); const int q2 = __shfl_xor(j2_1, off);
      if (better(u1, q1, a1_1, j1_1)) {
        float nv2; int ni2;
        if (better(a1_1, j1_1, u2, q2)) { nv2 = a1_1; ni2 = j1_1; }
        else                            { nv2 = u2;   ni2 = q2; }
        a1_1 = u1; j1_1 = q1; a2_1 = nv2; j2_1 = ni2;
      } else if (better(u1, q1, a2_1, j2_1)) { a2_1 = u1; j2_1 = q1; }
    }
  }

  const float e10 = __expf(a1_0), e20 = __expf(a2_0);
  const float rs0 = 1.f / (e10 + e20);
  const float w00 = e10 * rs0, w10 = e20 * rs0;
  const bool  fl0 = (a1_0 > 0.1f);
  const float xs00 = (float)(j1_0 % P), ys00 = (float)(j1_0 / P);
  const float xs10 = (float)(j2_0 % P), ys10 = (float)(j2_0 / P);

  const float e11 = __expf(a1_1), e21 = __expf(a2_1);
  const float rs1 = 1.f / (e11 + e21);
  const float w01 = e11 * rs1, w11 = e21 * rs1;
  const bool  fl1 = (a1_1 > 0.1f);
  const float xs01 = (float)(j1_1 % P), ys01 = (float)(j1_1 / P);
  const float xs11 = (float)(j2_1 % P), ys11 = (float)(j2_1 / P);

  #pragma unroll
  for (int k = 0; k < 6; ++k) {
    const int e = lane + 64 * k;
    if (e < NTOT) {
      const int r  = (e >= NWIN) ? 1 : 0;
      const int m  = e - r * NWIN;
      const int dy = m / P;
      const int dx = m - dy * P;
      const bool  fl = r ? fl1 : fl0;
      float val;
      if (fl) {
        const float wA = r ? w01 : w00, wB = r ? w11 : w10;
        const float xA = r ? xs01 : xs00, yA = r ? ys01 : ys00;
        const float xB = r ? xs11 : xs10, yB = r ? ys11 : ys10;
        const float fdx0 = (float)dx - xA, fdy0 = (float)dy - yA;
        const float fdx1 = (float)dx - xB, fdy1 = (float)dy - yB;
        val = wA * __expf(-FOUR_LN2 * (fdx0 * fdx0 + fdy0 * fdy0))
            + wB * __expf(-FOUR_LN2 * (fdx1 * fdx1 + fdy1 * fdy1));
      } else {
        val = p[k];
      }
      const int yy = y + dy - RAD;
      const int xx = x + dx - RAD;
      if ((unsigned)yy < 64u && (unsigned)xx < 64u) {
        const int cls = lab[(size_t)(r * 2 + b) * 4096 + yy * W + xx];
        atomicAdd(&accS[w][cls], val);
      }
    }
  }
  __syncthreads();

  if (t < 4 * NCLS) {
    const int cls = t >> 2;
    const int j   = t & 3;
    const int x0  = (blk * 4) & 63;
    const float sc = (cls == 0) ? 1.0f : 1.15f;
    out[(size_t)(b * NCLS + cls) * HW + y * W + x0 + j] = accS[j][cls] * sc;
  }
}

}  // namespace

extern "C" void kernel_launch(void* const* d_in, const int* in_sizes, int n_in,
                              void* d_out, int out_size, void* d_ws, size_t ws_size,
                              hipStream_t stream) {
  const float* fr = (const float*)d_in[0];   // feats_r
  const float* ft = (const float*)d_in[1];   // feats_t
  const int*   q  = (const int*)d_in[2];     // quantized_r
  float* out = (float*)d_out;
  float* vol = (float*)d_ws;                                   // 11,075,584 B
  int*   lab = (int*)((char*)d_ws + VOLF * sizeof(float));     // +64 KB
  float* zp  = (float*)((char*)lab + 16384 * sizeof(int));     // +4 KB zero page

  lab_kernel<<<dim3(64), dim3(256), 0, stream>>>(q, lab, zp);
  corr_kernel<<<dim3(2 * 2 * 64 * 2), dim3(256), 0, stream>>>(fr, ft, vol, zp);
  post_kernel<<<dim3(2 * HW / 4), dim3(256), 0, stream>>>(vol, lab, out);
}